// Round 3
// baseline (867.559 us; speedup 1.0000x reference)
//
#include <hip/hip_runtime.h>
#include <hip/hip_bf16.h>
#include <stdint.h>

// Problem constants (fixed by the reference)
#define HEADS 4
#define SLOPE 0.2f

typedef unsigned short u16;
typedef float f32x4 __attribute__((ext_vector_type(4)));
typedef short s16x8 __attribute__((ext_vector_type(8)));

__device__ __forceinline__ u16 f2bf(float f) {
    unsigned int u = __float_as_uint(f);
    u = (u + 0x7fffu + ((u >> 16) & 1u)) >> 16;   // round-to-nearest-even
    return (u16)u;
}
__device__ __forceinline__ float bf2f(u16 v) {
    return __uint_as_float(((unsigned int)v) << 16);
}
// finite-or-zero: if the fp32 dtype assumption is ever wrong, outputs stay
// finite (diagnosable absmax) instead of NaN.
__device__ __forceinline__ float fin(float x) {
    return (x == x && fabsf(x) < 1e30f) ? x : 0.f;
}

// ---------------------------------------------------------------- zero fill
__global__ void zero_kernel(int* __restrict__ p, int n) {
    int i = blockIdx.x * blockDim.x + threadIdx.x;
    if (i < n) p[i] = 0;
}

// ---------------------------------------------------------------- fp32 -> bf16 cast
__global__ void cast_kernel(const float* __restrict__ x, u16* __restrict__ y, int n) {
    int i = blockIdx.x * blockDim.x + threadIdx.x;
    if (i < n) y[i] = f2bf(fin(x[i]));
}

// ---------------------------------------------------------------- transpose+cast
// W fp32 [K x M] row-major -> Wt bf16 [M x K] row-major (B-frags K-contiguous)
__global__ void transpose_kernel(const float* __restrict__ W, u16* __restrict__ Wt,
                                 int K, int M) {
    int i = blockIdx.x * blockDim.x + threadIdx.x;
    if (i < K * M) {
        int k = i / M, m = i - k * M;
        Wt[m * K + k] = f2bf(fin(W[i]));
    }
}

// ---------------------------------------------------------------- CSR build
__global__ void count_kernel(const int* __restrict__ dst, int* __restrict__ deg,
                             int E, int N) {
    int i = blockIdx.x * blockDim.x + threadIdx.x;
    if (i < E + N) {
        int d = (i < E) ? dst[i] : (i - E);   // self-loops appended
        d = ((unsigned)d < (unsigned)N) ? d : 0;
        atomicAdd(&deg[d], 1);
    }
}

__global__ void scan_kernel(const int* __restrict__ deg, int* __restrict__ rowstart,
                            int* __restrict__ cursor, int N) {
    __shared__ int sm[1024];
    __shared__ int carry_s;
    int tid = threadIdx.x;
    if (tid == 0) carry_s = 0;
    __syncthreads();
    for (int base = 0; base < N; base += 1024) {
        int i = base + tid;
        int v = (i < N) ? deg[i] : 0;
        sm[tid] = v;
        __syncthreads();
        for (int off = 1; off < 1024; off <<= 1) {
            int t = (tid >= off) ? sm[tid - off] : 0;
            __syncthreads();
            sm[tid] += t;
            __syncthreads();
        }
        int excl = sm[tid] - v + carry_s;
        if (i < N) { rowstart[i] = excl; cursor[i] = excl; }
        int total = sm[1023];
        __syncthreads();
        if (tid == 0) carry_s += total;
        __syncthreads();
    }
    if (tid == 0) rowstart[N] = carry_s;
}

__global__ void scatter_kernel(const int* __restrict__ src, const int* __restrict__ dst,
                               int* __restrict__ cursor, int* __restrict__ csr,
                               int E, int N) {
    int i = blockIdx.x * blockDim.x + threadIdx.x;
    if (i < E + N) {
        int s, d;
        if (i < E) { s = src[i]; d = dst[i]; }
        else       { s = i - E; d = i - E; }
        s = ((unsigned)s < (unsigned)N) ? s : 0;
        d = ((unsigned)d < (unsigned)N) ? d : 0;
        int pos = atomicAdd(&cursor[d], 1);
        if ((unsigned)pos < (unsigned)(E + N)) csr[pos] = s;
    }
}

// ---------------------------------------------------------------- GEMM (bf16 MFMA, fp32 out)
// Hf[N x 256] = Xb[N x K] @ W[K x 256]; W pre-transposed+cast Wt[256 x K] bf16.
// Block 256 thr = 4 waves; block tile 64 rows x 256 cols; wave tile 32x128 =
// 2x8 MFMA 16x16x32. No LDS: A/B frags are 16B contiguous global loads (Wt L2-hot).
__global__ __launch_bounds__(256) void gemm_kernel(
        const u16* __restrict__ X, const u16* __restrict__ Wt,
        float* __restrict__ Hout, int N, int K) {
    int wv = threadIdx.x >> 6, lane = threadIdx.x & 63;
    int quad = lane >> 4, l16 = lane & 15;
    int m0 = (blockIdx.x * 2 + (wv & 1)) * 32;
    int n0 = (wv >> 1) * 128;

    f32x4 acc[2][8];
    #pragma unroll
    for (int r = 0; r < 2; r++)
        #pragma unroll
        for (int c = 0; c < 8; c++) acc[r][c] = (f32x4){0.f, 0.f, 0.f, 0.f};

    for (int k0 = 0; k0 < K; k0 += 32) {
        s16x8 a[2], b[8];
        #pragma unroll
        for (int r = 0; r < 2; r++) {
            int row = m0 + r * 16 + l16;
            row = row < N ? row : N - 1;             // clamp; padding rows masked at store
            a[r] = *(const s16x8*)(X + (size_t)row * K + k0 + quad * 8);
        }
        #pragma unroll
        for (int c = 0; c < 8; c++) {
            int n = n0 + c * 16 + l16;
            b[c] = *(const s16x8*)(Wt + (size_t)n * K + k0 + quad * 8);
        }
        #pragma unroll
        for (int r = 0; r < 2; r++)
            #pragma unroll
            for (int c = 0; c < 8; c++)
                acc[r][c] = __builtin_amdgcn_mfma_f32_16x16x32_bf16(a[r], b[c], acc[r][c], 0, 0, 0);
    }

    // C/D layout (measured): col = lane&15, row = quad*4 + reg
    #pragma unroll
    for (int r = 0; r < 2; r++) {
        int rowb = m0 + r * 16 + quad * 4;
        #pragma unroll
        for (int c = 0; c < 8; c++) {
            int col = n0 + c * 16 + l16;
            #pragma unroll
            for (int j = 0; j < 4; j++) {
                int row = rowb + j;
                if (row < N) Hout[(size_t)row * 256 + col] = acc[r][c][j];
            }
        }
    }
}

// ---------------------------------------------------------------- per-node attention logits
// alpha_src[n][h] = sum_c h[n,h,c]*a_src[h,c]; likewise dst. One wave per node.
__global__ __launch_bounds__(256) void alphas_kernel(
        const float* __restrict__ Hf, const float* __restrict__ att_src,
        const float* __restrict__ att_dst, float* __restrict__ as_out,
        float* __restrict__ ad_out, int N) {
    int wv = threadIdx.x >> 6, lane = threadIdx.x & 63;
    int n = blockIdx.x * 4 + wv;
    if (n >= N) return;
    f32x4 hv = *(const f32x4*)(Hf + (size_t)n * 256 + lane * 4);
    f32x4 sv = *(const f32x4*)(att_src + lane * 4);
    f32x4 dv = *(const f32x4*)(att_dst + lane * 4);
    float ps = 0.f, pd = 0.f;
    #pragma unroll
    for (int j = 0; j < 4; j++) {
        float h = hv[j];
        ps += h * fin(sv[j]);
        pd += h * fin(dv[j]);
    }
    #pragma unroll
    for (int off = 1; off <= 8; off <<= 1) {      // reduce within each 16-lane quad
        ps += __shfl_xor(ps, off);
        pd += __shfl_xor(pd, off);
    }
    if ((lane & 15) == 0) {
        int head = lane >> 4;
        as_out[n * 4 + head] = ps;
        ad_out[n * 4 + head] = pd;
    }
}

// ---------------------------------------------------------------- softmax-aggregate
// One wave per destination node; lane = channel (64); 4 heads in registers.
// One-pass online softmax over the node's CSR edges; fused bias + ELU.
// Intermediate layers write bf16 (next GEMM's input); final layer writes fp32 d_out.
__global__ __launch_bounds__(256) void aggregate_kernel(
        const float* __restrict__ Hf, const float* __restrict__ asrc,
        const float* __restrict__ adst, const int* __restrict__ rowstart,
        const int* __restrict__ csr, const float* __restrict__ bias,
        u16* __restrict__ outb, float* __restrict__ outf, int write_f32,
        int N, int Etot) {
    int wv = threadIdx.x >> 6, lane = threadIdx.x & 63;
    int n = blockIdx.x * 4 + wv;
    if (n >= N) return;
    f32x4 adv = *(const f32x4*)(adst + n * 4);
    float m[HEADS], d[HEADS], acc[HEADS];
    #pragma unroll
    for (int h = 0; h < HEADS; h++) { m[h] = -1e30f; d[h] = 0.f; acc[h] = 0.f; }
    int i0 = rowstart[n], i1 = rowstart[n + 1];
    i0 = min(max(i0, 0), Etot);
    i1 = min(max(i1, i0), Etot);
    for (int i = i0; i < i1; i++) {
        int s = csr[i];
        s = ((unsigned)s < (unsigned)N) ? s : 0;
        f32x4 asv = *(const f32x4*)(asrc + s * 4);
        const float* hr = Hf + (size_t)s * 256 + lane;
        #pragma unroll
        for (int h = 0; h < HEADS; h++) {
            float e = asv[h] + adv[h];
            e = e > 0.f ? e : SLOPE * e;            // leaky_relu
            float nm = fmaxf(m[h], e);
            float sc = __expf(m[h] - nm);
            float w  = __expf(e - nm);
            float v  = hr[h * 64];
            d[h]   = d[h] * sc + w;
            acc[h] = acc[h] * sc + w * v;
            m[h]   = nm;
        }
    }
    #pragma unroll
    for (int h = 0; h < HEADS; h++) {
        float inv = (d[h] > 0.f) ? 1.f / d[h] : 0.f;
        float o = acc[h] * inv + fin(bias[h * 64 + lane]);
        o = o > 0.f ? o : (__expf(o) - 1.f);        // ELU (alpha=1)
        size_t idx = (size_t)n * 256 + h * 64 + lane;
        if (write_f32) outf[idx] = o;
        else           outb[idx] = f2bf(o);
    }
}

// ---------------------------------------------------------------- launch
extern "C" void kernel_launch(void* const* d_in, const int* in_sizes, int n_in,
                              void* d_out, int out_size, void* d_ws, size_t ws_size,
                              hipStream_t stream) {
    const float* inp  = (const float*)d_in[0];
    const int*   ei   = (const int*)d_in[1];
    const float* W1   = (const float*)d_in[2];
    const float* at_s1= (const float*)d_in[3];
    const float* at_d1= (const float*)d_in[4];
    const float* b1   = (const float*)d_in[5];
    const float* W2   = (const float*)d_in[6];
    const float* at_s2= (const float*)d_in[7];
    const float* at_d2= (const float*)d_in[8];
    const float* b2   = (const float*)d_in[9];
    const float* W3   = (const float*)d_in[10];
    const float* at_s3= (const float*)d_in[11];
    const float* at_d3= (const float*)d_in[12];
    const float* b3   = (const float*)d_in[13];

    const int N = in_sizes[0] / 128;   // 50000
    const int E = in_sizes[1] / 2;     // 800000
    const int Etot = E + N;
    const int* esrc = ei;
    const int* edst = ei + E;

    // Workspace layout (~83 MB)
    char* p = (char*)d_ws;
    auto alloc = [&](size_t b) -> void* {
        void* q = (void*)p;
        p += (b + 255) & ~(size_t)255;
        return q;
    };
    u16*   Xb       = (u16*)alloc((size_t)N * 256 * 2);     // bf16 GEMM input (ping)
    float* Hf       = (float*)alloc((size_t)N * 256 * 4);   // fp32 GEMM output
    u16*   Wt1      = (u16*)alloc((size_t)128 * 256 * 2);
    u16*   Wt2      = (u16*)alloc((size_t)256 * 256 * 2);
    u16*   Wt3      = (u16*)alloc((size_t)256 * 256 * 2);
    float* asb      = (float*)alloc((size_t)N * 4 * 4);
    float* adb      = (float*)alloc((size_t)N * 4 * 4);
    int*   deg      = (int*)alloc((size_t)N * 4);
    int*   rowstart = (int*)alloc((size_t)(N + 1) * 4);
    int*   cursor   = (int*)alloc((size_t)N * 4);
    int*   csr      = (int*)alloc((size_t)Etot * 4);
    float* outf     = (float*)d_out;

    // CSR build (edge_index identical across layers — build once per launch)
    zero_kernel<<<(N + 255) / 256, 256, 0, stream>>>(deg, N);
    cast_kernel<<<(N * 128 + 255) / 256, 256, 0, stream>>>(inp, Xb, N * 128);
    transpose_kernel<<<(128 * 256 + 255) / 256, 256, 0, stream>>>(W1, Wt1, 128, 256);
    transpose_kernel<<<(256 * 256 + 255) / 256, 256, 0, stream>>>(W2, Wt2, 256, 256);
    transpose_kernel<<<(256 * 256 + 255) / 256, 256, 0, stream>>>(W3, Wt3, 256, 256);
    count_kernel<<<(Etot + 255) / 256, 256, 0, stream>>>(edst, deg, E, N);
    scan_kernel<<<1, 1024, 0, stream>>>(deg, rowstart, cursor, N);
    scatter_kernel<<<(Etot + 255) / 256, 256, 0, stream>>>(esrc, edst, cursor, csr, E, N);

    const int gemm_grid = (N + 63) / 64;
    const int node_grid = (N + 3) / 4;

    // layer 1 (K=128): Xb holds bf16(inp)
    gemm_kernel<<<gemm_grid, 256, 0, stream>>>(Xb, Wt1, Hf, N, 128);
    alphas_kernel<<<node_grid, 256, 0, stream>>>(Hf, at_s1, at_d1, asb, adb, N);
    aggregate_kernel<<<node_grid, 256, 0, stream>>>(Hf, asb, adb, rowstart, csr, b1,
                                                    Xb, outf, 0, N, Etot);

    // layer 2 (K=256): Xb now holds bf16(h1)
    gemm_kernel<<<gemm_grid, 256, 0, stream>>>(Xb, Wt2, Hf, N, 256);
    alphas_kernel<<<node_grid, 256, 0, stream>>>(Hf, at_s2, at_d2, asb, adb, N);
    aggregate_kernel<<<node_grid, 256, 0, stream>>>(Hf, asb, adb, rowstart, csr, b2,
                                                    Xb, outf, 0, N, Etot);

    // layer 3 (K=256) -> fp32 d_out
    gemm_kernel<<<gemm_grid, 256, 0, stream>>>(Xb, Wt3, Hf, N, 256);
    alphas_kernel<<<node_grid, 256, 0, stream>>>(Hf, at_s3, at_d3, asb, adb, N);
    aggregate_kernel<<<node_grid, 256, 0, stream>>>(Hf, asb, adb, rowstart, csr, b3,
                                                    Xb, outf, 1, N, Etot);
}

// Round 4
// 821.961 us; speedup vs baseline: 1.0555x; 1.0555x over previous
//
#include <hip/hip_runtime.h>
#include <hip/hip_bf16.h>
#include <stdint.h>

#define HEADS 4
#define SLOPE 0.2f

typedef unsigned short u16;
typedef float f32x4 __attribute__((ext_vector_type(4)));
typedef short s16x8 __attribute__((ext_vector_type(8)));
typedef unsigned short u16x4 __attribute__((ext_vector_type(4)));

__device__ __forceinline__ u16 f2bf(float f) {
    unsigned int u = __float_as_uint(f);
    u = (u + 0x7fffu + ((u >> 16) & 1u)) >> 16;   // round-to-nearest-even
    return (u16)u;
}
__device__ __forceinline__ float bf2f(u16 v) {
    return __uint_as_float(((unsigned int)v) << 16);
}
__device__ __forceinline__ float fin(float x) {
    return (x == x && fabsf(x) < 1e30f) ? x : 0.f;
}

// ---------------------------------------------------------------- zero fill
__global__ void zero_kernel(int* __restrict__ p, int n) {
    int i = blockIdx.x * blockDim.x + threadIdx.x;
    if (i < n) p[i] = 0;
}

// ---------------------------------------------------------------- fp32 -> bf16 cast
__global__ void cast_kernel(const float* __restrict__ x, u16* __restrict__ y, int n) {
    int i = blockIdx.x * blockDim.x + threadIdx.x;
    if (i < n) y[i] = f2bf(fin(x[i]));
}

// ---------------------------------------------------------------- transpose+cast
// W fp32 [K x M] row-major -> Wt bf16 [M x K] row-major (B-frags K-contiguous)
__global__ void transpose_kernel(const float* __restrict__ W, u16* __restrict__ Wt,
                                 int K, int M) {
    int i = blockIdx.x * blockDim.x + threadIdx.x;
    if (i < K * M) {
        int k = i / M, m = i - k * M;
        Wt[m * K + k] = f2bf(fin(W[i]));
    }
}

// ---------------------------------------------------------------- CSR build
__global__ void count_kernel(const int* __restrict__ dst, int* __restrict__ deg,
                             int E, int N) {
    int i = blockIdx.x * blockDim.x + threadIdx.x;
    if (i < E + N) {
        int d = (i < E) ? dst[i] : (i - E);   // self-loops appended
        d = ((unsigned)d < (unsigned)N) ? d : 0;
        atomicAdd(&deg[d], 1);
    }
}

// Single block; per-thread serial chunk + one 1024-wide block scan.
__global__ void scan_kernel(const int* __restrict__ deg, int* __restrict__ rowstart,
                            int* __restrict__ cursor, int N) {
    __shared__ int sm[1024];
    int tid = threadIdx.x;
    int chunk = (N + 1023) / 1024;
    int lo = tid * chunk, hi = min(lo + chunk, N);
    int s = 0;
    for (int i = lo; i < hi; i++) s += deg[i];
    sm[tid] = s;
    __syncthreads();
    for (int off = 1; off < 1024; off <<= 1) {
        int t = (tid >= off) ? sm[tid - off] : 0;
        __syncthreads();
        sm[tid] += t;
        __syncthreads();
    }
    int run = sm[tid] - s;                 // exclusive prefix for this chunk
    for (int i = lo; i < hi; i++) {
        rowstart[i] = run; cursor[i] = run;
        run += deg[i];
    }
    if (tid == 1023) rowstart[N] = sm[1023];
}

__global__ void scatter_kernel(const int* __restrict__ src, const int* __restrict__ dst,
                               int* __restrict__ cursor, int* __restrict__ csr,
                               int E, int N) {
    int i = blockIdx.x * blockDim.x + threadIdx.x;
    if (i < E + N) {
        int s, d;
        if (i < E) { s = src[i]; d = dst[i]; }
        else       { s = i - E; d = i - E; }
        s = ((unsigned)s < (unsigned)N) ? s : 0;
        d = ((unsigned)d < (unsigned)N) ? d : 0;
        int pos = atomicAdd(&cursor[d], 1);
        if ((unsigned)pos < (unsigned)(E + N)) csr[pos] = s;
    }
}

// ---------------------------------------------------------------- GEMM (bf16 MFMA, bf16 out)
// Hb[N x 256] = Xb[N x K] @ W[K x 256]; Wt[256 x K] bf16 pre-transposed.
// 4 waves/block, block tile 64x256, wave tile 32x128 = 2x8 MFMA 16x16x32.
__global__ __launch_bounds__(256) void gemm_kernel(
        const u16* __restrict__ X, const u16* __restrict__ Wt,
        u16* __restrict__ Hout, int N, int K) {
    int wv = threadIdx.x >> 6, lane = threadIdx.x & 63;
    int quad = lane >> 4, l16 = lane & 15;
    int m0 = (blockIdx.x * 2 + (wv & 1)) * 32;
    int n0 = (wv >> 1) * 128;

    f32x4 acc[2][8];
    #pragma unroll
    for (int r = 0; r < 2; r++)
        #pragma unroll
        for (int c = 0; c < 8; c++) acc[r][c] = (f32x4){0.f, 0.f, 0.f, 0.f};

    for (int k0 = 0; k0 < K; k0 += 32) {
        s16x8 a[2], b[8];
        #pragma unroll
        for (int r = 0; r < 2; r++) {
            int row = m0 + r * 16 + l16;
            row = row < N ? row : N - 1;             // clamp; masked at store
            a[r] = *(const s16x8*)(X + (size_t)row * K + k0 + quad * 8);
        }
        #pragma unroll
        for (int c = 0; c < 8; c++) {
            int n = n0 + c * 16 + l16;
            b[c] = *(const s16x8*)(Wt + (size_t)n * K + k0 + quad * 8);
        }
        #pragma unroll
        for (int r = 0; r < 2; r++)
            #pragma unroll
            for (int c = 0; c < 8; c++)
                acc[r][c] = __builtin_amdgcn_mfma_f32_16x16x32_bf16(a[r], b[c], acc[r][c], 0, 0, 0);
    }

    // C/D layout: col = lane&15, row = quad*4 + reg
    #pragma unroll
    for (int r = 0; r < 2; r++) {
        int rowb = m0 + r * 16 + quad * 4;
        #pragma unroll
        for (int c = 0; c < 8; c++) {
            int col = n0 + c * 16 + l16;
            #pragma unroll
            for (int j = 0; j < 4; j++) {
                int row = rowb + j;
                if (row < N) Hout[(size_t)row * 256 + col] = f2bf(acc[r][c][j]);
            }
        }
    }
}

// ---------------------------------------------------------------- per-node logits
// lane covers channels lane*4..+3 (head = lane>>4); quad-reduce sums each head.
__global__ __launch_bounds__(256) void alphas_kernel(
        const u16* __restrict__ Hb, const float* __restrict__ att_src,
        const float* __restrict__ att_dst, float* __restrict__ as_out,
        float* __restrict__ ad_out, int N) {
    int wv = threadIdx.x >> 6, lane = threadIdx.x & 63;
    int n = blockIdx.x * 4 + wv;
    if (n >= N) return;
    u16x4 hv = *(const u16x4*)(Hb + (size_t)n * 256 + lane * 4);
    f32x4 sv = *(const f32x4*)(att_src + lane * 4);
    f32x4 dv = *(const f32x4*)(att_dst + lane * 4);
    float ps = 0.f, pd = 0.f;
    #pragma unroll
    for (int j = 0; j < 4; j++) {
        float h = bf2f(hv[j]);
        ps += h * fin(sv[j]);
        pd += h * fin(dv[j]);
    }
    #pragma unroll
    for (int off = 1; off <= 8; off <<= 1) {
        ps += __shfl_xor(ps, off);
        pd += __shfl_xor(pd, off);
    }
    if ((lane & 15) == 0) {
        int head = lane >> 4;
        as_out[n * 4 + head] = ps;
        ad_out[n * 4 + head] = pd;
    }
}

// ---------------------------------------------------------------- edge softmax weights
// Wave per node, LANE PER EDGE (no 64x redundancy). Two passes over the node's
// edges: (1) per-head max, (2) w = exp(e-max) -> ew[], sum -> inv[].
__global__ __launch_bounds__(256) void weights_kernel(
        const float* __restrict__ asrc, const float* __restrict__ adst,
        const int* __restrict__ rowstart, const int* __restrict__ csr,
        float* __restrict__ ew, float* __restrict__ inv4, int N, int Etot) {
    int wv = threadIdx.x >> 6, lane = threadIdx.x & 63;
    int n = blockIdx.x * 4 + wv;
    if (n >= N) return;
    f32x4 adv = *(const f32x4*)(adst + n * 4);
    int i0 = rowstart[n], i1 = rowstart[n + 1];
    i0 = min(max(i0, 0), Etot);
    i1 = min(max(i1, i0), Etot);

    float mx[HEADS];
    #pragma unroll
    for (int h = 0; h < HEADS; h++) mx[h] = -1e30f;
    for (int i = i0 + lane; i < i1; i += 64) {
        int s = csr[i];
        s = ((unsigned)s < (unsigned)N) ? s : 0;
        f32x4 asv = *(const f32x4*)(asrc + s * 4);
        #pragma unroll
        for (int h = 0; h < HEADS; h++) {
            float e = asv[h] + adv[h];
            e = e > 0.f ? e : SLOPE * e;
            mx[h] = fmaxf(mx[h], e);
        }
    }
    #pragma unroll
    for (int off = 1; off <= 32; off <<= 1)
        #pragma unroll
        for (int h = 0; h < HEADS; h++)
            mx[h] = fmaxf(mx[h], __shfl_xor(mx[h], off));

    float sm[HEADS];
    #pragma unroll
    for (int h = 0; h < HEADS; h++) sm[h] = 0.f;
    for (int i = i0 + lane; i < i1; i += 64) {
        int s = csr[i];
        s = ((unsigned)s < (unsigned)N) ? s : 0;
        f32x4 asv = *(const f32x4*)(asrc + s * 4);
        f32x4 w;
        #pragma unroll
        for (int h = 0; h < HEADS; h++) {
            float e = asv[h] + adv[h];
            e = e > 0.f ? e : SLOPE * e;
            w[h] = __expf(e - mx[h]);
            sm[h] += w[h];
        }
        *(f32x4*)(ew + (size_t)i * 4) = w;
    }
    #pragma unroll
    for (int off = 1; off <= 32; off <<= 1)
        #pragma unroll
        for (int h = 0; h < HEADS; h++)
            sm[h] += __shfl_xor(sm[h], off);
    if (lane == 0) {
        f32x4 iv;
        #pragma unroll
        for (int h = 0; h < HEADS; h++) iv[h] = (sm[h] > 0.f) ? 1.f / sm[h] : 0.f;
        *(f32x4*)(inv4 + n * 4) = iv;
    }
}

// ---------------------------------------------------------------- weighted gather
// Wave per node, lane = channels lane*4..+3 (head = lane>>4).
// acc += ew[i][h] * Hb[s]; epilogue: *inv, +bias, ELU; bf16 (+ fp32 final) out.
__global__ __launch_bounds__(256) void gather_kernel(
        const u16* __restrict__ Hb, const float* __restrict__ ew,
        const float* __restrict__ inv4, const int* __restrict__ rowstart,
        const int* __restrict__ csr, const float* __restrict__ bias,
        u16* __restrict__ outb, float* __restrict__ outf, int write_f32,
        int N, int Etot) {
    int wv = threadIdx.x >> 6, lane = threadIdx.x & 63;
    int n = blockIdx.x * 4 + wv;
    if (n >= N) return;
    int h = lane >> 4;
    int i0 = rowstart[n], i1 = rowstart[n + 1];
    i0 = min(max(i0, 0), Etot);
    i1 = min(max(i1, i0), Etot);

    f32x4 acc = (f32x4){0.f, 0.f, 0.f, 0.f};
    for (int i = i0; i < i1; i++) {
        int s = csr[i];
        s = ((unsigned)s < (unsigned)N) ? s : 0;
        float wh = ew[((size_t)i << 2) + h];
        u16x4 hv = *(const u16x4*)(Hb + (size_t)s * 256 + lane * 4);
        #pragma unroll
        for (int j = 0; j < 4; j++) acc[j] += wh * bf2f(hv[j]);
    }
    float invh = inv4[n * 4 + h];
    f32x4 bv = *(const f32x4*)(bias + lane * 4);
    size_t base = (size_t)n * 256 + lane * 4;
    if (write_f32) {
        f32x4 o;
        #pragma unroll
        for (int j = 0; j < 4; j++) {
            float v = acc[j] * invh + fin(bv[j]);
            o[j] = v > 0.f ? v : (__expf(v) - 1.f);
        }
        *(f32x4*)(outf + base) = o;
    } else {
        u16x4 o;
        #pragma unroll
        for (int j = 0; j < 4; j++) {
            float v = acc[j] * invh + fin(bv[j]);
            v = v > 0.f ? v : (__expf(v) - 1.f);
            o[j] = f2bf(v);
        }
        *(u16x4*)(outb + base) = o;
    }
}

// ---------------------------------------------------------------- launch
extern "C" void kernel_launch(void* const* d_in, const int* in_sizes, int n_in,
                              void* d_out, int out_size, void* d_ws, size_t ws_size,
                              hipStream_t stream) {
    const float* inp  = (const float*)d_in[0];
    const int*   ei   = (const int*)d_in[1];
    const float* W1   = (const float*)d_in[2];
    const float* at_s1= (const float*)d_in[3];
    const float* at_d1= (const float*)d_in[4];
    const float* b1   = (const float*)d_in[5];
    const float* W2   = (const float*)d_in[6];
    const float* at_s2= (const float*)d_in[7];
    const float* at_d2= (const float*)d_in[8];
    const float* b2   = (const float*)d_in[9];
    const float* W3   = (const float*)d_in[10];
    const float* at_s3= (const float*)d_in[11];
    const float* at_d3= (const float*)d_in[12];
    const float* b3   = (const float*)d_in[13];

    const int N = in_sizes[0] / 128;   // 50000
    const int E = in_sizes[1] / 2;     // 800000
    const int Etot = E + N;
    const int* esrc = ei;
    const int* edst = ei + E;

    // Workspace (~71 MB)
    char* p = (char*)d_ws;
    auto alloc = [&](size_t b) -> void* {
        void* q = (void*)p;
        p += (b + 255) & ~(size_t)255;
        return q;
    };
    u16*   Xb       = (u16*)alloc((size_t)N * 256 * 2);     // bf16 GEMM input
    u16*   Hb       = (u16*)alloc((size_t)N * 256 * 2);     // bf16 features
    u16*   Wt1      = (u16*)alloc((size_t)128 * 256 * 2);
    u16*   Wt2      = (u16*)alloc((size_t)256 * 256 * 2);
    u16*   Wt3      = (u16*)alloc((size_t)256 * 256 * 2);
    float* asb      = (float*)alloc((size_t)N * 4 * 4);
    float* adb      = (float*)alloc((size_t)N * 4 * 4);
    float* inv4     = (float*)alloc((size_t)N * 4 * 4);
    float* ew       = (float*)alloc((size_t)Etot * 4 * 4);  // per-edge softmax weights
    int*   deg      = (int*)alloc((size_t)N * 4);
    int*   rowstart = (int*)alloc((size_t)(N + 1) * 4);
    int*   cursor   = (int*)alloc((size_t)N * 4);
    int*   csr      = (int*)alloc((size_t)Etot * 4);
    float* outf     = (float*)d_out;

    // CSR build (identical across layers — once per launch)
    zero_kernel<<<(N + 255) / 256, 256, 0, stream>>>(deg, N);
    cast_kernel<<<(N * 128 + 255) / 256, 256, 0, stream>>>(inp, Xb, N * 128);
    transpose_kernel<<<(128 * 256 + 255) / 256, 256, 0, stream>>>(W1, Wt1, 128, 256);
    transpose_kernel<<<(256 * 256 + 255) / 256, 256, 0, stream>>>(W2, Wt2, 256, 256);
    transpose_kernel<<<(256 * 256 + 255) / 256, 256, 0, stream>>>(W3, Wt3, 256, 256);
    count_kernel<<<(Etot + 255) / 256, 256, 0, stream>>>(edst, deg, E, N);
    scan_kernel<<<1, 1024, 0, stream>>>(deg, rowstart, cursor, N);
    scatter_kernel<<<(Etot + 255) / 256, 256, 0, stream>>>(esrc, edst, cursor, csr, E, N);

    const int gemm_grid = (N + 63) / 64;
    const int node_grid = (N + 3) / 4;

    // layer 1 (K=128)
    gemm_kernel<<<gemm_grid, 256, 0, stream>>>(Xb, Wt1, Hb, N, 128);
    alphas_kernel<<<node_grid, 256, 0, stream>>>(Hb, at_s1, at_d1, asb, adb, N);
    weights_kernel<<<node_grid, 256, 0, stream>>>(asb, adb, rowstart, csr, ew, inv4, N, Etot);
    gather_kernel<<<node_grid, 256, 0, stream>>>(Hb, ew, inv4, rowstart, csr, b1,
                                                 Xb, outf, 0, N, Etot);
    // layer 2 (K=256)
    gemm_kernel<<<gemm_grid, 256, 0, stream>>>(Xb, Wt2, Hb, N, 256);
    alphas_kernel<<<node_grid, 256, 0, stream>>>(Hb, at_s2, at_d2, asb, adb, N);
    weights_kernel<<<node_grid, 256, 0, stream>>>(asb, adb, rowstart, csr, ew, inv4, N, Etot);
    gather_kernel<<<node_grid, 256, 0, stream>>>(Hb, ew, inv4, rowstart, csr, b2,
                                                 Xb, outf, 0, N, Etot);
    // layer 3 (K=256) -> fp32 d_out
    gemm_kernel<<<gemm_grid, 256, 0, stream>>>(Xb, Wt3, Hb, N, 256);
    alphas_kernel<<<node_grid, 256, 0, stream>>>(Hb, at_s3, at_d3, asb, adb, N);
    weights_kernel<<<node_grid, 256, 0, stream>>>(asb, adb, rowstart, csr, ew, inv4, N, Etot);
    gather_kernel<<<node_grid, 256, 0, stream>>>(Hb, ew, inv4, rowstart, csr, b3,
                                                 Xb, outf, 1, N, Etot);
}

// Round 5
// 582.904 us; speedup vs baseline: 1.4883x; 1.4101x over previous
//
#include <hip/hip_runtime.h>
#include <hip/hip_bf16.h>
#include <stdint.h>

#define HEADS 4
#define SLOPE 0.2f

typedef unsigned short u16;
typedef float f32x4 __attribute__((ext_vector_type(4)));
typedef short s16x8 __attribute__((ext_vector_type(8)));
typedef unsigned short u16x4 __attribute__((ext_vector_type(4)));

__device__ __forceinline__ u16 f2bf(float f) {
    unsigned int u = __float_as_uint(f);
    u = (u + 0x7fffu + ((u >> 16) & 1u)) >> 16;   // round-to-nearest-even
    return (u16)u;
}
__device__ __forceinline__ float bf2f(u16 v) {
    return __uint_as_float(((unsigned int)v) << 16);
}
__device__ __forceinline__ float fin(float x) {
    return (x == x && fabsf(x) < 1e30f) ? x : 0.f;
}

// ---------------------------------------------------------------- zero fill
__global__ void zero_kernel(int* __restrict__ p, int n) {
    int i = blockIdx.x * blockDim.x + threadIdx.x;
    if (i < n) p[i] = 0;
}

// ---------------------------------------------------------------- fp32 -> bf16 cast
__global__ void cast_kernel(const float* __restrict__ x, u16* __restrict__ y, int n) {
    int i = blockIdx.x * blockDim.x + threadIdx.x;
    if (i < n) y[i] = f2bf(fin(x[i]));
}

// ---------------------------------------------------------------- transpose+cast
__global__ void transpose_kernel(const float* __restrict__ W, u16* __restrict__ Wt,
                                 int K, int M) {
    int i = blockIdx.x * blockDim.x + threadIdx.x;
    if (i < K * M) {
        int k = i / M, m = i - k * M;
        Wt[m * K + k] = f2bf(fin(W[i]));
    }
}

// ---------------------------------------------------------------- CSR build
__global__ void count_kernel(const int* __restrict__ dst, int* __restrict__ deg,
                             int E, int N) {
    int i = blockIdx.x * blockDim.x + threadIdx.x;
    if (i < E + N) {
        int d = (i < E) ? dst[i] : (i - E);   // self-loops appended
        d = ((unsigned)d < (unsigned)N) ? d : 0;
        atomicAdd(&deg[d], 1);
    }
}

// Hierarchical scan: blocksum (49 blocks) -> scanb (1 block) -> scan3 (49 blocks).
// Replaces the single-block serial scan that was 110 us (latency-bound, 1 CU).
__global__ __launch_bounds__(256) void blocksum_kernel(const int* __restrict__ deg,
                                                       int* __restrict__ bsum, int N) {
    int tid = threadIdx.x;
    int base = blockIdx.x * 1024 + tid * 4;
    int s = 0;
    #pragma unroll
    for (int j = 0; j < 4; j++) { int i = base + j; if (i < N) s += deg[i]; }
    #pragma unroll
    for (int off = 1; off <= 32; off <<= 1) s += __shfl_xor(s, off);
    __shared__ int sm[4];
    if ((tid & 63) == 0) sm[tid >> 6] = s;
    __syncthreads();
    if (tid == 0) bsum[blockIdx.x] = sm[0] + sm[1] + sm[2] + sm[3];
}

__global__ __launch_bounds__(256) void scanb_kernel(const int* __restrict__ bsum,
                                                    int* __restrict__ boff,
                                                    int* __restrict__ rowstart,
                                                    int B, int N) {
    __shared__ int sm[256];
    int tid = threadIdx.x;
    int v = (tid < B) ? bsum[tid] : 0;
    sm[tid] = v;
    __syncthreads();
    for (int off = 1; off < 256; off <<= 1) {
        int t = (tid >= off) ? sm[tid - off] : 0;
        __syncthreads();
        sm[tid] += t;
        __syncthreads();
    }
    if (tid < B) boff[tid] = sm[tid] - v;
    if (tid == 255) rowstart[N] = sm[255];   // grand total (padding contributes 0)
}

__global__ __launch_bounds__(256) void scan3_kernel(const int* __restrict__ deg,
                                                    const int* __restrict__ boff,
                                                    int* __restrict__ rowstart,
                                                    int* __restrict__ cursor, int N) {
    __shared__ int sm[256];
    int tid = threadIdx.x;
    int base = blockIdx.x * 1024 + tid * 4;
    int v[4]; int s = 0;
    #pragma unroll
    for (int j = 0; j < 4; j++) { int i = base + j; v[j] = (i < N) ? deg[i] : 0; s += v[j]; }
    sm[tid] = s;
    __syncthreads();
    for (int off = 1; off < 256; off <<= 1) {
        int t = (tid >= off) ? sm[tid - off] : 0;
        __syncthreads();
        sm[tid] += t;
        __syncthreads();
    }
    int run = boff[blockIdx.x] + sm[tid] - s;
    #pragma unroll
    for (int j = 0; j < 4; j++) {
        int i = base + j;
        if (i < N) { rowstart[i] = run; cursor[i] = run; run += v[j]; }
    }
}

__global__ void scatter_kernel(const int* __restrict__ src, const int* __restrict__ dst,
                               int* __restrict__ cursor, int* __restrict__ csr,
                               int E, int N) {
    int i = blockIdx.x * blockDim.x + threadIdx.x;
    if (i < E + N) {
        int s, d;
        if (i < E) { s = src[i]; d = dst[i]; }
        else       { s = i - E; d = i - E; }
        s = ((unsigned)s < (unsigned)N) ? s : 0;
        d = ((unsigned)d < (unsigned)N) ? d : 0;
        int pos = atomicAdd(&cursor[d], 1);
        if ((unsigned)pos < (unsigned)(E + N)) csr[pos] = s;
    }
}

// ---------------------------------------------------------------- GEMM (bf16 MFMA, bf16 out)
__global__ __launch_bounds__(256) void gemm_kernel(
        const u16* __restrict__ X, const u16* __restrict__ Wt,
        u16* __restrict__ Hout, int N, int K) {
    int wv = threadIdx.x >> 6, lane = threadIdx.x & 63;
    int quad = lane >> 4, l16 = lane & 15;
    int m0 = (blockIdx.x * 2 + (wv & 1)) * 32;
    int n0 = (wv >> 1) * 128;

    f32x4 acc[2][8];
    #pragma unroll
    for (int r = 0; r < 2; r++)
        #pragma unroll
        for (int c = 0; c < 8; c++) acc[r][c] = (f32x4){0.f, 0.f, 0.f, 0.f};

    for (int k0 = 0; k0 < K; k0 += 32) {
        s16x8 a[2], b[8];
        #pragma unroll
        for (int r = 0; r < 2; r++) {
            int row = m0 + r * 16 + l16;
            row = row < N ? row : N - 1;
            a[r] = *(const s16x8*)(X + (size_t)row * K + k0 + quad * 8);
        }
        #pragma unroll
        for (int c = 0; c < 8; c++) {
            int n = n0 + c * 16 + l16;
            b[c] = *(const s16x8*)(Wt + (size_t)n * K + k0 + quad * 8);
        }
        #pragma unroll
        for (int r = 0; r < 2; r++)
            #pragma unroll
            for (int c = 0; c < 8; c++)
                acc[r][c] = __builtin_amdgcn_mfma_f32_16x16x32_bf16(a[r], b[c], acc[r][c], 0, 0, 0);
    }

    #pragma unroll
    for (int r = 0; r < 2; r++) {
        int rowb = m0 + r * 16 + quad * 4;
        #pragma unroll
        for (int c = 0; c < 8; c++) {
            int col = n0 + c * 16 + l16;
            #pragma unroll
            for (int j = 0; j < 4; j++) {
                int row = rowb + j;
                if (row < N) Hout[(size_t)row * 256 + col] = f2bf(acc[r][c][j]);
            }
        }
    }
}

// ---------------------------------------------------------------- per-node logits
__global__ __launch_bounds__(256) void alphas_kernel(
        const u16* __restrict__ Hb, const float* __restrict__ att_src,
        const float* __restrict__ att_dst, float* __restrict__ as_out,
        float* __restrict__ ad_out, int N) {
    int wv = threadIdx.x >> 6, lane = threadIdx.x & 63;
    int n = blockIdx.x * 4 + wv;
    if (n >= N) return;
    u16x4 hv = *(const u16x4*)(Hb + (size_t)n * 256 + lane * 4);
    f32x4 sv = *(const f32x4*)(att_src + lane * 4);
    f32x4 dv = *(const f32x4*)(att_dst + lane * 4);
    float ps = 0.f, pd = 0.f;
    #pragma unroll
    for (int j = 0; j < 4; j++) {
        float h = bf2f(hv[j]);
        ps += h * fin(sv[j]);
        pd += h * fin(dv[j]);
    }
    #pragma unroll
    for (int off = 1; off <= 8; off <<= 1) {
        ps += __shfl_xor(ps, off);
        pd += __shfl_xor(pd, off);
    }
    if ((lane & 15) == 0) {
        int head = lane >> 4;
        as_out[n * 4 + head] = ps;
        ad_out[n * 4 + head] = pd;
    }
}

// ---------------------------------------------------------------- edge softmax weights
// Single pass (no max-subtraction: |e| <~ 12, clamp 80 for hard safety).
// 16 lanes per node (4 nodes/wave, 16 nodes/block) — avg degree ~17, so the
// old 64-lane version idled 47 lanes.
__global__ __launch_bounds__(256) void weights_kernel(
        const float* __restrict__ asrc, const float* __restrict__ adst,
        const int* __restrict__ rowstart, const int* __restrict__ csr,
        float* __restrict__ ew, float* __restrict__ inv4, int N, int Etot) {
    int wv = threadIdx.x >> 6, lane = threadIdx.x & 63;
    int g = lane >> 4, l = lane & 15;
    int n = blockIdx.x * 16 + wv * 4 + g;
    if (n >= N) return;
    f32x4 adv = *(const f32x4*)(adst + n * 4);
    int i0 = rowstart[n], i1 = rowstart[n + 1];
    i0 = min(max(i0, 0), Etot);
    i1 = min(max(i1, i0), Etot);

    float sm[HEADS];
    #pragma unroll
    for (int h = 0; h < HEADS; h++) sm[h] = 0.f;
    for (int i = i0 + l; i < i1; i += 16) {
        int s = csr[i];
        s = ((unsigned)s < (unsigned)N) ? s : 0;
        f32x4 asv = *(const f32x4*)(asrc + s * 4);
        f32x4 w;
        #pragma unroll
        for (int h = 0; h < HEADS; h++) {
            float e = asv[h] + adv[h];
            e = e > 0.f ? e : SLOPE * e;        // leaky_relu
            e = fminf(e, 80.f);                 // overflow guard (exp(80)=5e34 < fp32 max)
            w[h] = __expf(e);
            sm[h] += w[h];
        }
        *(f32x4*)(ew + (size_t)i * 4) = w;
    }
    #pragma unroll
    for (int off = 1; off <= 8; off <<= 1)
        #pragma unroll
        for (int h = 0; h < HEADS; h++)
            sm[h] += __shfl_xor(sm[h], off);
    if (l == 0) {
        f32x4 iv;
        #pragma unroll
        for (int h = 0; h < HEADS; h++) iv[h] = (sm[h] > 0.f) ? 1.f / sm[h] : 0.f;
        *(f32x4*)(inv4 + n * 4) = iv;
    }
}

// ---------------------------------------------------------------- weighted gather
// Wave per node; 2 edges per iteration (half-wave each); lane covers 8 channels
// (16 B u16x8 load — coalescing sweet spot). Cross-half merge via shfl_xor(32).
__global__ __launch_bounds__(256) void gather_kernel(
        const u16* __restrict__ Hb, const float* __restrict__ ew,
        const float* __restrict__ inv4, const int* __restrict__ rowstart,
        const int* __restrict__ csr, const float* __restrict__ bias,
        u16* __restrict__ outb, float* __restrict__ outf, int write_f32,
        int N, int Etot) {
    int wv = threadIdx.x >> 6, lane = threadIdx.x & 63;
    int n = blockIdx.x * 4 + wv;
    if (n >= N) return;
    int es = lane >> 5, c = lane & 31;    // half-wave edge slot; 8-channel group
    int h = c >> 3;
    int i0 = rowstart[n], i1 = rowstart[n + 1];
    i0 = min(max(i0, 0), Etot);
    i1 = min(max(i1, i0), Etot);

    float acc[8];
    #pragma unroll
    for (int j = 0; j < 8; j++) acc[j] = 0.f;
    for (int i = i0 + es; i < i1; i += 2) {
        int s = csr[i];
        s = ((unsigned)s < (unsigned)N) ? s : 0;
        float wh = ew[((size_t)i << 2) + h];
        s16x8 hv = *(const s16x8*)(Hb + (size_t)s * 256 + c * 8);
        #pragma unroll
        for (int j = 0; j < 8; j++) acc[j] += wh * bf2f((u16)hv[j]);
    }
    #pragma unroll
    for (int j = 0; j < 8; j++) acc[j] += __shfl_xor(acc[j], 32);

    if (es == 0) {
        float invh = inv4[n * 4 + h];
        f32x4 blo = *(const f32x4*)(bias + c * 8);
        f32x4 bhi = *(const f32x4*)(bias + c * 8 + 4);
        size_t base = (size_t)n * 256 + c * 8;
        float o[8];
        #pragma unroll
        for (int j = 0; j < 8; j++) {
            float v = acc[j] * invh + fin(j < 4 ? blo[j] : bhi[j - 4]);
            o[j] = v > 0.f ? v : (__expf(v) - 1.f);   // ELU
        }
        if (write_f32) {
            f32x4 lo = {o[0], o[1], o[2], o[3]}, hi = {o[4], o[5], o[6], o[7]};
            *(f32x4*)(outf + base) = lo;
            *(f32x4*)(outf + base + 4) = hi;
        } else {
            s16x8 ob;
            #pragma unroll
            for (int j = 0; j < 8; j++) ob[j] = (short)f2bf(o[j]);
            *(s16x8*)(outb + base) = ob;
        }
    }
}

// ---------------------------------------------------------------- launch
extern "C" void kernel_launch(void* const* d_in, const int* in_sizes, int n_in,
                              void* d_out, int out_size, void* d_ws, size_t ws_size,
                              hipStream_t stream) {
    const float* inp  = (const float*)d_in[0];
    const int*   ei   = (const int*)d_in[1];
    const float* W1   = (const float*)d_in[2];
    const float* at_s1= (const float*)d_in[3];
    const float* at_d1= (const float*)d_in[4];
    const float* b1   = (const float*)d_in[5];
    const float* W2   = (const float*)d_in[6];
    const float* at_s2= (const float*)d_in[7];
    const float* at_d2= (const float*)d_in[8];
    const float* b2   = (const float*)d_in[9];
    const float* W3   = (const float*)d_in[10];
    const float* at_s3= (const float*)d_in[11];
    const float* at_d3= (const float*)d_in[12];
    const float* b3   = (const float*)d_in[13];

    const int N = in_sizes[0] / 128;   // 50000
    const int E = in_sizes[1] / 2;     // 800000
    const int Etot = E + N;
    const int* esrc = ei;
    const int* edst = ei + E;

    char* p = (char*)d_ws;
    auto alloc = [&](size_t b) -> void* {
        void* q = (void*)p;
        p += (b + 255) & ~(size_t)255;
        return q;
    };
    u16*   Xb       = (u16*)alloc((size_t)N * 256 * 2);
    u16*   Hb       = (u16*)alloc((size_t)N * 256 * 2);
    u16*   Wt1      = (u16*)alloc((size_t)128 * 256 * 2);
    u16*   Wt2      = (u16*)alloc((size_t)256 * 256 * 2);
    u16*   Wt3      = (u16*)alloc((size_t)256 * 256 * 2);
    float* asb      = (float*)alloc((size_t)N * 4 * 4);
    float* adb      = (float*)alloc((size_t)N * 4 * 4);
    float* inv4     = (float*)alloc((size_t)N * 4 * 4);
    float* ew       = (float*)alloc((size_t)Etot * 4 * 4);
    int*   deg      = (int*)alloc((size_t)N * 4);
    int*   rowstart = (int*)alloc((size_t)(N + 1) * 4);
    int*   cursor   = (int*)alloc((size_t)N * 4);
    int*   csr      = (int*)alloc((size_t)Etot * 4);
    int*   bsum     = (int*)alloc((size_t)256 * 4);
    int*   boff     = (int*)alloc((size_t)256 * 4);
    float* outf     = (float*)d_out;

    const int SB = (N + 1023) / 1024;   // scan blocks (49)

    // CSR build (identical across layers — once per launch)
    zero_kernel<<<(N + 255) / 256, 256, 0, stream>>>(deg, N);
    cast_kernel<<<(N * 128 + 255) / 256, 256, 0, stream>>>(inp, Xb, N * 128);
    transpose_kernel<<<(128 * 256 + 255) / 256, 256, 0, stream>>>(W1, Wt1, 128, 256);
    transpose_kernel<<<(256 * 256 + 255) / 256, 256, 0, stream>>>(W2, Wt2, 256, 256);
    transpose_kernel<<<(256 * 256 + 255) / 256, 256, 0, stream>>>(W3, Wt3, 256, 256);
    count_kernel<<<(Etot + 255) / 256, 256, 0, stream>>>(edst, deg, E, N);
    blocksum_kernel<<<SB, 256, 0, stream>>>(deg, bsum, N);
    scanb_kernel<<<1, 256, 0, stream>>>(bsum, boff, rowstart, SB, N);
    scan3_kernel<<<SB, 256, 0, stream>>>(deg, boff, rowstart, cursor, N);
    scatter_kernel<<<(Etot + 255) / 256, 256, 0, stream>>>(esrc, edst, cursor, csr, E, N);

    const int gemm_grid = (N + 63) / 64;
    const int node_grid = (N + 3) / 4;
    const int wnode_grid = (N + 15) / 16;

    // layer 1 (K=128)
    gemm_kernel<<<gemm_grid, 256, 0, stream>>>(Xb, Wt1, Hb, N, 128);
    alphas_kernel<<<node_grid, 256, 0, stream>>>(Hb, at_s1, at_d1, asb, adb, N);
    weights_kernel<<<wnode_grid, 256, 0, stream>>>(asb, adb, rowstart, csr, ew, inv4, N, Etot);
    gather_kernel<<<node_grid, 256, 0, stream>>>(Hb, ew, inv4, rowstart, csr, b1,
                                                 Xb, outf, 0, N, Etot);
    // layer 2 (K=256)
    gemm_kernel<<<gemm_grid, 256, 0, stream>>>(Xb, Wt2, Hb, N, 256);
    alphas_kernel<<<node_grid, 256, 0, stream>>>(Hb, at_s2, at_d2, asb, adb, N);
    weights_kernel<<<wnode_grid, 256, 0, stream>>>(asb, adb, rowstart, csr, ew, inv4, N, Etot);
    gather_kernel<<<node_grid, 256, 0, stream>>>(Hb, ew, inv4, rowstart, csr, b2,
                                                 Xb, outf, 0, N, Etot);
    // layer 3 (K=256) -> fp32 d_out
    gemm_kernel<<<gemm_grid, 256, 0, stream>>>(Xb, Wt3, Hb, N, 256);
    alphas_kernel<<<node_grid, 256, 0, stream>>>(Hb, at_s3, at_d3, asb, adb, N);
    weights_kernel<<<wnode_grid, 256, 0, stream>>>(asb, adb, rowstart, csr, ew, inv4, N, Etot);
    gather_kernel<<<node_grid, 256, 0, stream>>>(Hb, ew, inv4, rowstart, csr, b3,
                                                 Xb, outf, 1, N, Etot);
}

// Round 6
// 544.388 us; speedup vs baseline: 1.5936x; 1.0708x over previous
//
#include <hip/hip_runtime.h>
#include <hip/hip_bf16.h>
#include <stdint.h>

#define HEADS 4
#define SLOPE 0.2f

typedef unsigned short u16;
typedef float f32x4 __attribute__((ext_vector_type(4)));
typedef short s16x8 __attribute__((ext_vector_type(8)));
typedef unsigned short u16x4 __attribute__((ext_vector_type(4)));

__device__ __forceinline__ u16 f2bf(float f) {
    unsigned int u = __float_as_uint(f);
    u = (u + 0x7fffu + ((u >> 16) & 1u)) >> 16;   // round-to-nearest-even
    return (u16)u;
}
__device__ __forceinline__ float bf2f(u16 v) {
    return __uint_as_float(((unsigned int)v) << 16);
}
__device__ __forceinline__ float fin(float x) {
    return (x == x && fabsf(x) < 1e30f) ? x : 0.f;
}

// ---------------------------------------------------------------- zero fill
__global__ void zero_kernel(int* __restrict__ p, int n) {
    int i = blockIdx.x * blockDim.x + threadIdx.x;
    if (i < n) p[i] = 0;
}

// ---------------------------------------------------------------- fp32 -> bf16 cast
__global__ void cast_kernel(const float* __restrict__ x, u16* __restrict__ y, int n) {
    int i = blockIdx.x * blockDim.x + threadIdx.x;
    if (i < n) y[i] = f2bf(fin(x[i]));
}

// ---------------------------------------------------------------- transpose+cast
__global__ void transpose_kernel(const float* __restrict__ W, u16* __restrict__ Wt,
                                 int K, int M) {
    int i = blockIdx.x * blockDim.x + threadIdx.x;
    if (i < K * M) {
        int k = i / M, m = i - k * M;
        Wt[m * K + k] = f2bf(fin(W[i]));
    }
}

// ---------------------------------------------------------------- CSR build
__global__ void count_kernel(const int* __restrict__ dst, int* __restrict__ deg,
                             int E, int N) {
    int i = blockIdx.x * blockDim.x + threadIdx.x;
    if (i < E + N) {
        int d = (i < E) ? dst[i] : (i - E);   // self-loops appended
        d = ((unsigned)d < (unsigned)N) ? d : 0;
        atomicAdd(&deg[d], 1);
    }
}

// Hierarchical scan: blocksum (49 blocks) -> scanb (1 block) -> scan3 (49 blocks).
__global__ __launch_bounds__(256) void blocksum_kernel(const int* __restrict__ deg,
                                                       int* __restrict__ bsum, int N) {
    int tid = threadIdx.x;
    int base = blockIdx.x * 1024 + tid * 4;
    int s = 0;
    #pragma unroll
    for (int j = 0; j < 4; j++) { int i = base + j; if (i < N) s += deg[i]; }
    #pragma unroll
    for (int off = 1; off <= 32; off <<= 1) s += __shfl_xor(s, off);
    __shared__ int sm[4];
    if ((tid & 63) == 0) sm[tid >> 6] = s;
    __syncthreads();
    if (tid == 0) bsum[blockIdx.x] = sm[0] + sm[1] + sm[2] + sm[3];
}

__global__ __launch_bounds__(256) void scanb_kernel(const int* __restrict__ bsum,
                                                    int* __restrict__ boff,
                                                    int* __restrict__ rowstart,
                                                    int B, int N) {
    __shared__ int sm[256];
    int tid = threadIdx.x;
    int v = (tid < B) ? bsum[tid] : 0;
    sm[tid] = v;
    __syncthreads();
    for (int off = 1; off < 256; off <<= 1) {
        int t = (tid >= off) ? sm[tid - off] : 0;
        __syncthreads();
        sm[tid] += t;
        __syncthreads();
    }
    if (tid < B) boff[tid] = sm[tid] - v;
    if (tid == 255) rowstart[N] = sm[255];
}

__global__ __launch_bounds__(256) void scan3_kernel(const int* __restrict__ deg,
                                                    const int* __restrict__ boff,
                                                    int* __restrict__ rowstart,
                                                    int* __restrict__ cursor, int N) {
    __shared__ int sm[256];
    int tid = threadIdx.x;
    int base = blockIdx.x * 1024 + tid * 4;
    int v[4]; int s = 0;
    #pragma unroll
    for (int j = 0; j < 4; j++) { int i = base + j; v[j] = (i < N) ? deg[i] : 0; s += v[j]; }
    sm[tid] = s;
    __syncthreads();
    for (int off = 1; off < 256; off <<= 1) {
        int t = (tid >= off) ? sm[tid - off] : 0;
        __syncthreads();
        sm[tid] += t;
        __syncthreads();
    }
    int run = boff[blockIdx.x] + sm[tid] - s;
    #pragma unroll
    for (int j = 0; j < 4; j++) {
        int i = base + j;
        if (i < N) { rowstart[i] = run; cursor[i] = run; run += v[j]; }
    }
}

__global__ void scatter_kernel(const int* __restrict__ src, const int* __restrict__ dst,
                               int* __restrict__ cursor, int* __restrict__ csr,
                               int E, int N) {
    int i = blockIdx.x * blockDim.x + threadIdx.x;
    if (i < E + N) {
        int s, d;
        if (i < E) { s = src[i]; d = dst[i]; }
        else       { s = i - E; d = i - E; }
        s = ((unsigned)s < (unsigned)N) ? s : 0;
        d = ((unsigned)d < (unsigned)N) ? d : 0;
        int pos = atomicAdd(&cursor[d], 1);
        if ((unsigned)pos < (unsigned)(E + N)) csr[pos] = s;
    }
}

// ---------------------------------------------------------------- GEMM (bf16 MFMA, bf16 out)
__global__ __launch_bounds__(256) void gemm_kernel(
        const u16* __restrict__ X, const u16* __restrict__ Wt,
        u16* __restrict__ Hout, int N, int K) {
    int wv = threadIdx.x >> 6, lane = threadIdx.x & 63;
    int quad = lane >> 4, l16 = lane & 15;
    int m0 = (blockIdx.x * 2 + (wv & 1)) * 32;
    int n0 = (wv >> 1) * 128;

    f32x4 acc[2][8];
    #pragma unroll
    for (int r = 0; r < 2; r++)
        #pragma unroll
        for (int c = 0; c < 8; c++) acc[r][c] = (f32x4){0.f, 0.f, 0.f, 0.f};

    for (int k0 = 0; k0 < K; k0 += 32) {
        s16x8 a[2], b[8];
        #pragma unroll
        for (int r = 0; r < 2; r++) {
            int row = m0 + r * 16 + l16;
            row = row < N ? row : N - 1;
            a[r] = *(const s16x8*)(X + (size_t)row * K + k0 + quad * 8);
        }
        #pragma unroll
        for (int c = 0; c < 8; c++) {
            int n = n0 + c * 16 + l16;
            b[c] = *(const s16x8*)(Wt + (size_t)n * K + k0 + quad * 8);
        }
        #pragma unroll
        for (int r = 0; r < 2; r++)
            #pragma unroll
            for (int c = 0; c < 8; c++)
                acc[r][c] = __builtin_amdgcn_mfma_f32_16x16x32_bf16(a[r], b[c], acc[r][c], 0, 0, 0);
    }

    #pragma unroll
    for (int r = 0; r < 2; r++) {
        int rowb = m0 + r * 16 + quad * 4;
        #pragma unroll
        for (int c = 0; c < 8; c++) {
            int col = n0 + c * 16 + l16;
            #pragma unroll
            for (int j = 0; j < 4; j++) {
                int row = rowb + j;
                if (row < N) Hout[(size_t)row * 256 + col] = f2bf(acc[r][c][j]);
            }
        }
    }
}

// ---------------------------------------------------------------- per-node logits
__global__ __launch_bounds__(256) void alphas_kernel(
        const u16* __restrict__ Hb, const float* __restrict__ att_src,
        const float* __restrict__ att_dst, float* __restrict__ as_out,
        float* __restrict__ ad_out, int N) {
    int wv = threadIdx.x >> 6, lane = threadIdx.x & 63;
    int n = blockIdx.x * 4 + wv;
    if (n >= N) return;
    u16x4 hv = *(const u16x4*)(Hb + (size_t)n * 256 + lane * 4);
    f32x4 sv = *(const f32x4*)(att_src + lane * 4);
    f32x4 dv = *(const f32x4*)(att_dst + lane * 4);
    float ps = 0.f, pd = 0.f;
    #pragma unroll
    for (int j = 0; j < 4; j++) {
        float h = bf2f(hv[j]);
        ps += h * fin(sv[j]);
        pd += h * fin(dv[j]);
    }
    #pragma unroll
    for (int off = 1; off <= 8; off <<= 1) {
        ps += __shfl_xor(ps, off);
        pd += __shfl_xor(pd, off);
    }
    if ((lane & 15) == 0) {
        int head = lane >> 4;
        as_out[n * 4 + head] = ps;
        ad_out[n * 4 + head] = pd;
    }
}

// ---------------------------------------------------------------- fused softmax-gather
// Wave per node; 2 half-wave edge slots; lane covers 8 channels (16 B load) of
// head h = (lane&31)>>3. Softmax weight computed INLINE (max-free, clamp 80):
// acc += exp(e)*v, ws += exp(e); epilogue: acc/ws + bias, ELU.
// Edge loop unrolled x2 per slot -> 4 independent row loads in flight per wave.
__global__ __launch_bounds__(256) void gather_kernel(
        const u16* __restrict__ Hb, const float* __restrict__ asrc,
        const float* __restrict__ adst, const int* __restrict__ rowstart,
        const int* __restrict__ csr, const float* __restrict__ bias,
        u16* __restrict__ outb, float* __restrict__ outf, int write_f32,
        int N, int Etot) {
    int wv = threadIdx.x >> 6, lane = threadIdx.x & 63;
    int n = blockIdx.x * 4 + wv;
    if (n >= N) return;
    int es = lane >> 5, c = lane & 31;    // edge slot; 8-channel group
    int h = c >> 3;
    int i0 = rowstart[n], i1 = rowstart[n + 1];
    i0 = min(max(i0, 0), Etot);
    i1 = min(max(i1, i0), Etot);

    float adh = adst[n * 4 + h];
    float acc[8];
    float ws = 0.f;
    #pragma unroll
    for (int j = 0; j < 8; j++) acc[j] = 0.f;

    int i = i0 + es;
    // 2 edges per slot per iteration: 4 independent csr/asrc/row loads in flight
    for (; i + 2 < i1; i += 4) {
        int sA = csr[i], sB = csr[i + 2];
        sA = ((unsigned)sA < (unsigned)N) ? sA : 0;
        sB = ((unsigned)sB < (unsigned)N) ? sB : 0;
        float eA = asrc[sA * 4 + h] + adh;
        float eB = asrc[sB * 4 + h] + adh;
        s16x8 hvA = *(const s16x8*)(Hb + (size_t)sA * 256 + c * 8);
        s16x8 hvB = *(const s16x8*)(Hb + (size_t)sB * 256 + c * 8);
        eA = eA > 0.f ? eA : SLOPE * eA;
        eB = eB > 0.f ? eB : SLOPE * eB;
        float wA = __expf(fminf(eA, 80.f));
        float wB = __expf(fminf(eB, 80.f));
        ws += wA + wB;
        #pragma unroll
        for (int j = 0; j < 8; j++)
            acc[j] += wA * bf2f((u16)hvA[j]) + wB * bf2f((u16)hvB[j]);
    }
    if (i < i1) {
        int s = csr[i];
        s = ((unsigned)s < (unsigned)N) ? s : 0;
        float e = asrc[s * 4 + h] + adh;
        s16x8 hv = *(const s16x8*)(Hb + (size_t)s * 256 + c * 8);
        e = e > 0.f ? e : SLOPE * e;
        float w = __expf(fminf(e, 80.f));
        ws += w;
        #pragma unroll
        for (int j = 0; j < 8; j++) acc[j] += w * bf2f((u16)hv[j]);
    }

    // merge the two edge slots
    ws += __shfl_xor(ws, 32);
    #pragma unroll
    for (int j = 0; j < 8; j++) acc[j] += __shfl_xor(acc[j], 32);

    if (es == 0) {
        float invh = (ws > 0.f) ? 1.f / ws : 0.f;
        f32x4 blo = *(const f32x4*)(bias + c * 8);
        f32x4 bhi = *(const f32x4*)(bias + c * 8 + 4);
        size_t base = (size_t)n * 256 + c * 8;
        float o[8];
        #pragma unroll
        for (int j = 0; j < 8; j++) {
            float v = acc[j] * invh + fin(j < 4 ? blo[j] : bhi[j - 4]);
            o[j] = v > 0.f ? v : (__expf(v) - 1.f);   // ELU
        }
        if (write_f32) {
            f32x4 lo = {o[0], o[1], o[2], o[3]}, hi = {o[4], o[5], o[6], o[7]};
            *(f32x4*)(outf + base) = lo;
            *(f32x4*)(outf + base + 4) = hi;
        } else {
            s16x8 ob;
            #pragma unroll
            for (int j = 0; j < 8; j++) ob[j] = (short)f2bf(o[j]);
            *(s16x8*)(outb + base) = ob;
        }
    }
}

// ---------------------------------------------------------------- launch
extern "C" void kernel_launch(void* const* d_in, const int* in_sizes, int n_in,
                              void* d_out, int out_size, void* d_ws, size_t ws_size,
                              hipStream_t stream) {
    const float* inp  = (const float*)d_in[0];
    const int*   ei   = (const int*)d_in[1];
    const float* W1   = (const float*)d_in[2];
    const float* at_s1= (const float*)d_in[3];
    const float* at_d1= (const float*)d_in[4];
    const float* b1   = (const float*)d_in[5];
    const float* W2   = (const float*)d_in[6];
    const float* at_s2= (const float*)d_in[7];
    const float* at_d2= (const float*)d_in[8];
    const float* b2   = (const float*)d_in[9];
    const float* W3   = (const float*)d_in[10];
    const float* at_s3= (const float*)d_in[11];
    const float* at_d3= (const float*)d_in[12];
    const float* b3   = (const float*)d_in[13];

    const int N = in_sizes[0] / 128;   // 50000
    const int E = in_sizes[1] / 2;     // 800000
    const int Etot = E + N;
    const int* esrc = ei;
    const int* edst = ei + E;

    char* p = (char*)d_ws;
    auto alloc = [&](size_t b) -> void* {
        void* q = (void*)p;
        p += (b + 255) & ~(size_t)255;
        return q;
    };
    u16*   Xb       = (u16*)alloc((size_t)N * 256 * 2);
    u16*   Hb       = (u16*)alloc((size_t)N * 256 * 2);
    u16*   Wt1      = (u16*)alloc((size_t)128 * 256 * 2);
    u16*   Wt2      = (u16*)alloc((size_t)256 * 256 * 2);
    u16*   Wt3      = (u16*)alloc((size_t)256 * 256 * 2);
    float* asb      = (float*)alloc((size_t)N * 4 * 4);
    float* adb      = (float*)alloc((size_t)N * 4 * 4);
    int*   deg      = (int*)alloc((size_t)N * 4);
    int*   rowstart = (int*)alloc((size_t)(N + 1) * 4);
    int*   cursor   = (int*)alloc((size_t)N * 4);
    int*   csr      = (int*)alloc((size_t)Etot * 4);
    int*   bsum     = (int*)alloc((size_t)256 * 4);
    int*   boff     = (int*)alloc((size_t)256 * 4);
    float* outf     = (float*)d_out;

    const int SB = (N + 1023) / 1024;   // scan blocks (49)

    // CSR build (identical across layers — once per launch)
    zero_kernel<<<(N + 255) / 256, 256, 0, stream>>>(deg, N);
    cast_kernel<<<(N * 128 + 255) / 256, 256, 0, stream>>>(inp, Xb, N * 128);
    transpose_kernel<<<(128 * 256 + 255) / 256, 256, 0, stream>>>(W1, Wt1, 128, 256);
    transpose_kernel<<<(256 * 256 + 255) / 256, 256, 0, stream>>>(W2, Wt2, 256, 256);
    transpose_kernel<<<(256 * 256 + 255) / 256, 256, 0, stream>>>(W3, Wt3, 256, 256);
    count_kernel<<<(Etot + 255) / 256, 256, 0, stream>>>(edst, deg, E, N);
    blocksum_kernel<<<SB, 256, 0, stream>>>(deg, bsum, N);
    scanb_kernel<<<1, 256, 0, stream>>>(bsum, boff, rowstart, SB, N);
    scan3_kernel<<<SB, 256, 0, stream>>>(deg, boff, rowstart, cursor, N);
    scatter_kernel<<<(Etot + 255) / 256, 256, 0, stream>>>(esrc, edst, cursor, csr, E, N);

    const int gemm_grid = (N + 63) / 64;
    const int node_grid = (N + 3) / 4;

    // layer 1 (K=128)
    gemm_kernel<<<gemm_grid, 256, 0, stream>>>(Xb, Wt1, Hb, N, 128);
    alphas_kernel<<<node_grid, 256, 0, stream>>>(Hb, at_s1, at_d1, asb, adb, N);
    gather_kernel<<<node_grid, 256, 0, stream>>>(Hb, asb, adb, rowstart, csr, b1,
                                                 Xb, outf, 0, N, Etot);
    // layer 2 (K=256)
    gemm_kernel<<<gemm_grid, 256, 0, stream>>>(Xb, Wt2, Hb, N, 256);
    alphas_kernel<<<node_grid, 256, 0, stream>>>(Hb, at_s2, at_d2, asb, adb, N);
    gather_kernel<<<node_grid, 256, 0, stream>>>(Hb, asb, adb, rowstart, csr, b2,
                                                 Xb, outf, 0, N, Etot);
    // layer 3 (K=256) -> fp32 d_out
    gemm_kernel<<<gemm_grid, 256, 0, stream>>>(Xb, Wt3, Hb, N, 256);
    alphas_kernel<<<node_grid, 256, 0, stream>>>(Hb, at_s3, at_d3, asb, adb, N);
    gather_kernel<<<node_grid, 256, 0, stream>>>(Hb, asb, adb, rowstart, csr, b3,
                                                 Xb, outf, 1, N, Etot);
}